// Round 1
// baseline (334.939 us; speedup 1.0000x reference)
//
#include <hip/hip_runtime.h>
#include <math.h>

#define OUTSZ   224
#define NBINS   8
#define NTH     256
#define IMG_H   512
#define IMG_W   512
#define HWSZ    (IMG_H * IMG_W)          // 262144

// ---------------------------------------------------------------------------
// Pre-pass: (N,2,H,W) -> (N,H,W,2) interleaved float2.
// Each thread handles 4 pixels: 2x float4 loads, 2x float4 stores.
// ---------------------------------------------------------------------------
__global__ __launch_bounds__(NTH) void interleave_kernel(
    const float* __restrict__ f, float2* __restrict__ o, int total4)
{
    const int i = blockIdx.x * NTH + threadIdx.x;
    if (i >= total4) return;
    const int n   = i >> 16;                 // / (HWSZ/4) == 65536
    const int hw4 = (i & 65535) << 2;        // pixel offset within plane
    const float4 a = *reinterpret_cast<const float4*>(f + (size_t)n * 2 * HWSZ + hw4);
    const float4 b = *reinterpret_cast<const float4*>(f + (size_t)n * 2 * HWSZ + HWSZ + hw4);
    float4* d4 = reinterpret_cast<float4*>(o + (size_t)n * HWSZ + hw4);
    d4[0] = make_float4(a.x, b.x, a.y, b.y);
    d4[1] = make_float4(a.z, b.z, a.w, b.w);
}

// ---------------------------------------------------------------------------
// Main kernel. ILV=true: gathers float2 from interleaved copy (4 loads/sample)
//              ILV=false: gathers from the two separate planes (8 loads/sample)
// Histogram: per-(bin,tid) slots, updated with ds_add_f32 (fire-and-forget,
// no lgkmcnt wait, conflict-free: bank = tid & 31).
// ---------------------------------------------------------------------------
template <int CHUNKS, bool ILV>
__global__ __launch_bounds__(NTH) void velhist_kernel(
    const void* __restrict__ flows_,   // float2* (ILV) or float* (planes)
    const float* __restrict__ boxes,   // (M,5)
    float* __restrict__ ws,            // partials (CHUNKS>1): [grid][16]
    float* __restrict__ out)           // (M,8)  (CHUNKS==1 path)
{
    constexpr int RPC = OUTSZ / CHUNKS;   // rows per chunk (must be even)
    static_assert(RPC % 2 == 0, "unroll-2 needs even RPC");
    const int bid   = blockIdx.x;
    const int m     = (CHUNKS == 1) ? bid : (bid / CHUNKS);
    const int chunk = (CHUNKS == 1) ? 0   : (bid - m * CHUNKS);
    const int tid   = threadIdx.x;

    __shared__ float s_sum[NBINS * NTH];
    __shared__ float s_cnt[NBINS * NTH];

#pragma unroll
    for (int b = 0; b < NBINS; ++b) {
        s_sum[(b << 8) + tid] = 0.0f;
        s_cnt[(b << 8) + tid] = 0.0f;
    }

    const float bxf = boxes[m * 5 + 0];
    const float x1  = boxes[m * 5 + 1];
    const float y1  = boxes[m * 5 + 2];
    const float x2  = boxes[m * 5 + 3];
    const float y2  = boxes[m * 5 + 4];
    const int  bidx = (int)bxf;
    const float roi_w = fmaxf(x2 - x1, 1.0f);
    const float roi_h = fmaxf(y2 - y1, 1.0f);

    const float2* __restrict__ fb =
        ILV ? ((const float2*)flows_) + (size_t)bidx * HWSZ : nullptr;
    const float* __restrict__ f0 =
        ILV ? nullptr : ((const float*)flows_) + (size_t)bidx * 2 * HWSZ;
    const float* __restrict__ f1 = ILV ? nullptr : f0 + HWSZ;

    const float GINV = 1.0f / (float)OUTSZ;

    __syncthreads();

    if (tid < OUTSZ) {
        const int col = tid;
        // per-column x state (registers, computed once)
        const float gx  = ((float)col + 0.5f) * GINV;
        const float px  = x1 + gx * roi_w;
        const bool  vx  = (px >= -1.0f) && (px <= (float)IMG_W);
        const float pcx = fminf(fmaxf(px, 0.0f), (float)(IMG_W - 1));
        const int   x0  = (int)pcx;
        const float fx  = pcx - (float)x0;
        const int   x1i = min(x0 + 1, IMG_W - 1);
        const float wx0 = 1.0f - fx;

        auto do_row = [&](int row) {
            const float gy  = ((float)row + 0.5f) * GINV;
            const float py  = y1 + gy * roi_h;        // wave-uniform -> scalar
            const bool  vy  = (py >= -1.0f) && (py <= (float)IMG_H);
            const float pcy = fminf(fmaxf(py, 0.0f), (float)(IMG_H - 1));
            const int   y0  = (int)pcy;
            const float fy  = pcy - (float)y0;
            const int   y1r = min(y0 + 1, IMG_H - 1);
            const float wy0 = 1.0f - fy;

            const int r0 = y0  << 9;   // *512
            const int r1 = y1r << 9;

            const float w00 = wy0 * wx0, w01 = wy0 * fx;
            const float w10 = fy  * wx0, w11 = fy  * fx;

            float a, b;
            if constexpr (ILV) {
                const float2 c00 = fb[r0 + x0], c01 = fb[r0 + x1i];
                const float2 c10 = fb[r1 + x0], c11 = fb[r1 + x1i];
                a = (c00.x * w00 + c01.x * w01) + (c10.x * w10 + c11.x * w11);
                b = (c00.y * w00 + c01.y * w01) + (c10.y * w10 + c11.y * w11);
            } else {
                const int i00 = r0 + x0, i01 = r0 + x1i;
                const int i10 = r1 + x0, i11 = r1 + x1i;
                a = (f0[i00] * w00 + f0[i01] * w01) + (f0[i10] * w10 + f0[i11] * w11);
                b = (f1[i00] * w00 + f1[i01] * w01) + (f1[i10] * w10 + f1[i11] * w11);
            }

            float mag = sqrtf(a * a + b * b);

            // octant of atan2(a, b), Gray-decoded from 3 sign/compare bits
            const int p = (a >= 0.0f) ? 1 : 0;
            const int q = (b >= 0.0f) ? 1 : 0;
            const int t = (fabsf(a) >= fabsf(b)) ? 1 : 0;
            const int u = p ^ q;
            int bin = (p << 2) | (u << 1) | (u ^ t);

            const bool valid = vx && vy;
            if (!valid) { mag = 0.0f; bin = 4; }   // atan2(0,0)=0 -> bin 4

            const int hidx = (bin << 8) + tid;
            (void)__hip_atomic_fetch_add(&s_sum[hidx], mag, __ATOMIC_RELAXED,
                                         __HIP_MEMORY_SCOPE_WORKGROUP);
            (void)__hip_atomic_fetch_add(&s_cnt[hidx], 1.0f, __ATOMIC_RELAXED,
                                         __HIP_MEMORY_SCOPE_WORKGROUP);
        };

        for (int r = 0; r < RPC; r += 2) {
            const int row = chunk * RPC + r;
            do_row(row);
            do_row(row + 1);
        }
    }

    // tree-reduce 256 -> 1 per bin (both arrays)
    int sh = 7;
    for (int off = 128; off >= 1; off >>= 1, --sh) {
        __syncthreads();
        for (int w = tid; w < NBINS * off; w += NTH) {
            const int b = w >> sh;
            const int t = w & (off - 1);
            const int ix = (b << 8) + t;
            s_sum[ix] += s_sum[ix + off];
            s_cnt[ix] += s_cnt[ix + off];
        }
    }
    __syncthreads();

    if (tid < NBINS) {
        const float s = s_sum[tid << 8];
        const float c = s_cnt[tid << 8];
        if (CHUNKS == 1) {
            out[m * NBINS + tid] = (c != 0.0f) ? (s / fmaxf(c, 1.0f)) : 0.0f;
        } else {
            float* p = ws + bid * 16;
            p[tid]     = s;
            p[tid + 8] = c;
        }
    }
}

__global__ __launch_bounds__(NTH) void finalize_kernel(
    const float* __restrict__ ws, float* __restrict__ out, int M, int chunks)
{
    const int i = blockIdx.x * NTH + threadIdx.x;
    if (i >= M * NBINS) return;
    const int m = i >> 3;
    const int b = i & 7;
    float s = 0.0f, c = 0.0f;
    for (int ch = 0; ch < chunks; ++ch) {
        const float* p = ws + (size_t)(m * chunks + ch) * 16;
        s += p[b];
        c += p[b + 8];
    }
    out[i] = (c != 0.0f) ? (s / fmaxf(c, 1.0f)) : 0.0f;
}

extern "C" void kernel_launch(void* const* d_in, const int* in_sizes, int n_in,
                              void* d_out, int out_size, void* d_ws, size_t ws_size,
                              hipStream_t stream) {
    const float* flows = (const float*)d_in[0];
    const float* boxes = (const float*)d_in[1];
    float* out = (float*)d_out;
    const int M = in_sizes[1] / 5;               // 512
    const int N = in_sizes[0] / (2 * HWSZ);      // 8

    const int CH = 8;
    const size_t part_need = (size_t)M * CH * 16 * sizeof(float);      // 512 KB
    const size_t ilv_need  = (size_t)N * HWSZ * sizeof(float2);        // 16.78 MB

    if (ws_size >= ilv_need + part_need) {
        float2* fI  = (float2*)d_ws;
        float* part = (float*)d_ws + (size_t)N * HWSZ * 2;
        const int total4 = N * HWSZ / 4;
        interleave_kernel<<<dim3((total4 + NTH - 1) / NTH), dim3(NTH), 0, stream>>>(
            flows, fI, total4);
        velhist_kernel<CH, true><<<dim3(M * CH), dim3(NTH), 0, stream>>>(
            fI, boxes, part, nullptr);
        finalize_kernel<<<dim3((M * NBINS + NTH - 1) / NTH), dim3(NTH), 0, stream>>>(
            part, out, M, CH);
    } else if (ws_size >= part_need) {
        velhist_kernel<CH, false><<<dim3(M * CH), dim3(NTH), 0, stream>>>(
            flows, boxes, (float*)d_ws, nullptr);
        finalize_kernel<<<dim3((M * NBINS + NTH - 1) / NTH), dim3(NTH), 0, stream>>>(
            (const float*)d_ws, out, M, CH);
    } else {
        velhist_kernel<1, false><<<dim3(M), dim3(NTH), 0, stream>>>(
            flows, boxes, nullptr, out);
    }
}

// Round 2
// 128.609 us; speedup vs baseline: 2.6043x; 2.6043x over previous
//
#include <hip/hip_runtime.h>
#include <math.h>

#define OUTSZ   224
#define NBINS   8
#define NTH     256
#define IMG_H   512
#define IMG_W   512
#define HWSZ    (IMG_H * IMG_W)          // 262144

// ---------------------------------------------------------------------------
// Pre-pass: (N,2,H,W) -> (N,H,W,2) interleaved float2.
// Each thread handles 4 pixels: 2x float4 loads, 2x float4 stores.
// (verified correct in round 1)
// ---------------------------------------------------------------------------
__global__ __launch_bounds__(NTH) void interleave_kernel(
    const float* __restrict__ f, float2* __restrict__ o, int total4)
{
    const int i = blockIdx.x * NTH + threadIdx.x;
    if (i >= total4) return;
    const int n   = i >> 16;                 // / (HWSZ/4) == 65536
    const int hw4 = (i & 65535) << 2;        // pixel offset within plane
    const float4 a = *reinterpret_cast<const float4*>(f + (size_t)n * 2 * HWSZ + hw4);
    const float4 b = *reinterpret_cast<const float4*>(f + (size_t)n * 2 * HWSZ + HWSZ + hw4);
    float4* d4 = reinterpret_cast<float4*>(o + (size_t)n * HWSZ + hw4);
    d4[0] = make_float4(a.x, b.x, a.y, b.y);
    d4[1] = make_float4(a.z, b.z, a.w, b.w);
}

// ---------------------------------------------------------------------------
// Main kernel — round-0 structure (float2 LDS read-add-write histogram,
// NO LDS atomics: ds_add_f32 measured 3.7x slower in round 1).
// ILV=true: gathers float2 from interleaved copy (4 loads/sample).
// ---------------------------------------------------------------------------
template <int CHUNKS, bool ILV>
__global__ __launch_bounds__(NTH) void velhist_kernel(
    const void* __restrict__ flows_,   // float2* (ILV) or float* (planes)
    const float* __restrict__ boxes,   // (M,5)
    float* __restrict__ ws,            // partials (CHUNKS>1): [grid][16]
    float* __restrict__ out)           // (M,8)  (CHUNKS==1 path)
{
    constexpr int RPC = OUTSZ / CHUNKS;   // rows per chunk
    const int bid   = blockIdx.x;
    const int m     = (CHUNKS == 1) ? bid : (bid / CHUNKS);
    const int chunk = (CHUNKS == 1) ? 0   : (bid - m * CHUNKS);
    const int tid   = threadIdx.x;

    __shared__ float2 s_h[NBINS * NTH];   // {sum, cnt}

#pragma unroll
    for (int b = 0; b < NBINS; ++b)
        s_h[(b << 8) + tid] = make_float2(0.0f, 0.0f);

    const float bxf = boxes[m * 5 + 0];
    const float x1  = boxes[m * 5 + 1];
    const float y1  = boxes[m * 5 + 2];
    const float x2  = boxes[m * 5 + 3];
    const float y2  = boxes[m * 5 + 4];
    const int  bidx = (int)bxf;
    const float roi_w = fmaxf(x2 - x1, 1.0f);
    const float roi_h = fmaxf(y2 - y1, 1.0f);

    const float2* __restrict__ fb =
        ILV ? ((const float2*)flows_) + (size_t)bidx * HWSZ : nullptr;
    const float* __restrict__ f0 =
        ILV ? nullptr : ((const float*)flows_) + (size_t)bidx * 2 * HWSZ;
    const float* __restrict__ f1 = ILV ? nullptr : f0 + HWSZ;

    const float GINV = 1.0f / (float)OUTSZ;

    __syncthreads();

    if (tid < OUTSZ) {
        const int col = tid;
        // per-column x state (registers, computed once)
        const float gx  = ((float)col + 0.5f) * GINV;
        const float px  = x1 + gx * roi_w;
        const bool  vx  = (px >= -1.0f) && (px <= (float)IMG_W);
        const float pcx = fminf(fmaxf(px, 0.0f), (float)(IMG_W - 1));
        const int   x0  = (int)pcx;
        const float fx  = pcx - (float)x0;
        const int   x1i = min(x0 + 1, IMG_W - 1);
        const float wx0 = 1.0f - fx;

        for (int r = 0; r < RPC; ++r) {
            const int row = chunk * RPC + r;
            const float gy  = ((float)row + 0.5f) * GINV;
            const float py  = y1 + gy * roi_h;
            const bool  vy  = (py >= -1.0f) && (py <= (float)IMG_H);
            const float pcy = fminf(fmaxf(py, 0.0f), (float)(IMG_H - 1));
            const int   y0  = (int)pcy;
            const float fy  = pcy - (float)y0;
            const int   y1r = min(y0 + 1, IMG_H - 1);
            const float wy0 = 1.0f - fy;

            const int r0 = y0  << 9;   // *512
            const int r1 = y1r << 9;

            const float w00 = wy0 * wx0, w01 = wy0 * fx;
            const float w10 = fy  * wx0, w11 = fy  * fx;

            float a, b;
            if constexpr (ILV) {
                const float2 c00 = fb[r0 + x0], c01 = fb[r0 + x1i];
                const float2 c10 = fb[r1 + x0], c11 = fb[r1 + x1i];
                a = (c00.x * w00 + c01.x * w01) + (c10.x * w10 + c11.x * w11);
                b = (c00.y * w00 + c01.y * w01) + (c10.y * w10 + c11.y * w11);
            } else {
                const int i00 = r0 + x0, i01 = r0 + x1i;
                const int i10 = r1 + x0, i11 = r1 + x1i;
                a = (f0[i00] * w00 + f0[i01] * w01) + (f0[i10] * w10 + f0[i11] * w11);
                b = (f1[i00] * w00 + f1[i01] * w01) + (f1[i10] * w10 + f1[i11] * w11);
            }

            const bool valid = vx && vy;
            if (!valid) { a = 0.0f; b = 0.0f; }

            const float mag = sqrtf(a * a + b * b);

            // octant of atan2(a, b), Gray-decoded from 3 sign/compare bits
            const int p = (a >= 0.0f) ? 1 : 0;
            const int q = (b >= 0.0f) ? 1 : 0;
            const int t = (fabsf(a) >= fabsf(b)) ? 1 : 0;
            const int u = p ^ q;
            int bin = (p << 2) | (u << 1) | (u ^ t);
            if (!valid) bin = 4;   // atan2(0,0)=0 -> bin 4

            const int hidx = (bin << 8) + tid;
            float2 h = s_h[hidx];
            h.x += mag;
            h.y += 1.0f;
            s_h[hidx] = h;
        }
    }

    // tree-reduce 256 -> 1 per bin
    int sh = 7;
    for (int off = 128; off >= 1; off >>= 1, --sh) {
        __syncthreads();
        for (int w = tid; w < NBINS * off; w += NTH) {
            const int b = w >> sh;
            const int t = w & (off - 1);
            float2 lo = s_h[(b << 8) + t];
            float2 hi = s_h[(b << 8) + t + off];
            lo.x += hi.x; lo.y += hi.y;
            s_h[(b << 8) + t] = lo;
        }
    }
    __syncthreads();

    if (tid < NBINS) {
        const float2 h = s_h[tid << 8];
        if (CHUNKS == 1) {
            out[m * NBINS + tid] = (h.y != 0.0f) ? (h.x / fmaxf(h.y, 1.0f)) : 0.0f;
        } else {
            float* p = ws + bid * 16;
            p[tid]     = h.x;
            p[tid + 8] = h.y;
        }
    }
}

__global__ __launch_bounds__(NTH) void finalize_kernel(
    const float* __restrict__ ws, float* __restrict__ out, int M, int chunks)
{
    const int i = blockIdx.x * NTH + threadIdx.x;
    if (i >= M * NBINS) return;
    const int m = i >> 3;
    const int b = i & 7;
    float s = 0.0f, c = 0.0f;
    for (int ch = 0; ch < chunks; ++ch) {
        const float* p = ws + (size_t)(m * chunks + ch) * 16;
        s += p[b];
        c += p[b + 8];
    }
    out[i] = (c != 0.0f) ? (s / fmaxf(c, 1.0f)) : 0.0f;
}

extern "C" void kernel_launch(void* const* d_in, const int* in_sizes, int n_in,
                              void* d_out, int out_size, void* d_ws, size_t ws_size,
                              hipStream_t stream) {
    const float* flows = (const float*)d_in[0];
    const float* boxes = (const float*)d_in[1];
    float* out = (float*)d_out;
    const int M = in_sizes[1] / 5;               // 512
    const int N = in_sizes[0] / (2 * HWSZ);      // 8

    const int CH = 4;                            // 2048 blocks = 8/CU exact (round-0 proven)
    const size_t part_need = (size_t)M * CH * 16 * sizeof(float);      // 128 KB
    const size_t ilv_need  = (size_t)N * HWSZ * sizeof(float2);        // 16.78 MB

    if (ws_size >= ilv_need + part_need) {
        float2* fI  = (float2*)d_ws;
        float* part = (float*)d_ws + (size_t)N * HWSZ * 2;
        const int total4 = N * HWSZ / 4;
        interleave_kernel<<<dim3((total4 + NTH - 1) / NTH), dim3(NTH), 0, stream>>>(
            flows, fI, total4);
        velhist_kernel<CH, true><<<dim3(M * CH), dim3(NTH), 0, stream>>>(
            fI, boxes, part, nullptr);
        finalize_kernel<<<dim3((M * NBINS + NTH - 1) / NTH), dim3(NTH), 0, stream>>>(
            part, out, M, CH);
    } else if (ws_size >= part_need) {
        velhist_kernel<CH, false><<<dim3(M * CH), dim3(NTH), 0, stream>>>(
            flows, boxes, (float*)d_ws, nullptr);
        finalize_kernel<<<dim3((M * NBINS + NTH - 1) / NTH), dim3(NTH), 0, stream>>>(
            (const float*)d_ws, out, M, CH);
    } else {
        velhist_kernel<1, false><<<dim3(M), dim3(NTH), 0, stream>>>(
            flows, boxes, nullptr, out);
    }
}

// Round 3
// 115.238 us; speedup vs baseline: 2.9065x; 1.1160x over previous
//
#include <hip/hip_runtime.h>
#include <math.h>

#define OUTSZ   224
#define NBINS   8
#define NTH     448          // 7 full waves: lanes = (2 rows) x (224 cols)
#define FNTH    256
#define IMG_H   512
#define IMG_W   512
#define HWSZ    (IMG_H * IMG_W)   // 262144
#define SLOTS   512          // per-bin histogram slots (448 used, padded pow2)

// 8-byte pair load at 4-byte alignment (pixels x0, x0+1 of one channel row).
// gfx950 global loads support dword-aligned dwordx2; clang keeps it single.
typedef float f2u __attribute__((ext_vector_type(2), aligned(4)));

// ---------------------------------------------------------------------------
// Main kernel. Planar input (N,2,H,W) — NO pre-pass (round-2: pre-pass was
// net-negative). Corner pairs via single dwordx2 thanks to x0<=W-2 clamp
// (exact: weights absorb the shift, see proof in session notes).
// Histogram: float2 {sum,cnt} read-add-write per (bin, tid) slot — NO LDS
// atomics (round-1: ds_add_f32 measured 3.7x slower).
// ---------------------------------------------------------------------------
template <int CHUNKS>
__global__ __launch_bounds__(NTH) void velhist_kernel(
    const float* __restrict__ flows,   // (N,2,H,W)
    const float* __restrict__ boxes,   // (M,5)
    float* __restrict__ ws,            // partials (CHUNKS>1): [grid][16]
    float* __restrict__ out)           // (M,8)  (CHUNKS==1 path)
{
    constexpr int RPC = OUTSZ / CHUNKS;   // rows per chunk
    static_assert(RPC % 2 == 0, "row-pair layout needs even RPC");
    const int bid   = blockIdx.x;
    const int m     = (CHUNKS == 1) ? bid : (bid / CHUNKS);
    const int chunk = (CHUNKS == 1) ? 0   : (bid - m * CHUNKS);
    const int tid   = threadIdx.x;

    __shared__ float2 s_h[NBINS * SLOTS];   // 32 KB {sum, cnt}

    for (int w = tid; w < NBINS * SLOTS; w += NTH)
        s_h[w] = make_float2(0.0f, 0.0f);

    const float bxf = boxes[m * 5 + 0];
    const float x1  = boxes[m * 5 + 1];
    const float y1  = boxes[m * 5 + 2];
    const float x2  = boxes[m * 5 + 3];
    const float y2  = boxes[m * 5 + 4];
    const int  bidx = (int)bxf;
    const float roi_w = fmaxf(x2 - x1, 1.0f);
    const float roi_h = fmaxf(y2 - y1, 1.0f);

    const float* __restrict__ f0 = flows + (size_t)bidx * 2 * HWSZ;
    const float* __restrict__ f1 = f0 + HWSZ;

    const float GINV = 1.0f / (float)OUTSZ;

    // lane -> (row-offset, col):  lanes [0,224) row r, [224,448) row r+1
    const int half = (tid >= OUTSZ) ? 1 : 0;
    const int col  = tid - OUTSZ * half;

    // per-column x state (registers, computed once)
    const float gx  = ((float)col + 0.5f) * GINV;
    const float px  = x1 + gx * roi_w;
    const bool  vx  = (px >= -1.0f) && (px <= (float)IMG_W);
    const float pcx = fminf(fmaxf(px, 0.0f), (float)(IMG_W - 1));
    const int   x0  = min((int)pcx, IMG_W - 2);   // pair-load clamp (exact)
    const float fx  = pcx - (float)x0;
    const float wx0 = 1.0f - fx;

    __syncthreads();

#pragma unroll 2
    for (int rp = 0; rp < RPC; rp += 2) {
        const int row = chunk * RPC + rp + half;
        const float gy  = ((float)row + 0.5f) * GINV;
        const float py  = y1 + gy * roi_h;
        const bool  vy  = (py >= -1.0f) && (py <= (float)IMG_H);
        const float pcy = fminf(fmaxf(py, 0.0f), (float)(IMG_H - 1));
        const int   y0  = min((int)pcy, IMG_H - 2);   // pair-row clamp (exact)
        const float fy  = pcy - (float)y0;
        const float wy0 = 1.0f - fy;

        const int i0 = (y0 << 9) + x0;      // row y0, cols {x0, x0+1}
        const int i1 = i0 + IMG_W;          // row y0+1

        const float w00 = wy0 * wx0, w01 = wy0 * fx;
        const float w10 = fy  * wx0, w11 = fy  * fx;

        const f2u c0 = *reinterpret_cast<const f2u*>(f0 + i0);  // ch0 row0
        const f2u d0 = *reinterpret_cast<const f2u*>(f0 + i1);  // ch0 row1
        const f2u c1 = *reinterpret_cast<const f2u*>(f1 + i0);  // ch1 row0
        const f2u d1 = *reinterpret_cast<const f2u*>(f1 + i1);  // ch1 row1

        float a = (c0.x * w00 + c0.y * w01) + (d0.x * w10 + d0.y * w11);
        float b = (c1.x * w00 + c1.y * w01) + (d1.x * w10 + d1.y * w11);

        const bool valid = vx && vy;
        if (!valid) { a = 0.0f; b = 0.0f; }

        const float mag = __builtin_amdgcn_sqrtf(a * a + b * b);

        // octant of atan2(a, b), Gray-decoded from 3 sign/compare bits
        const int p = (a >= 0.0f) ? 1 : 0;
        const int q = (b >= 0.0f) ? 1 : 0;
        const int t = (fabsf(a) >= fabsf(b)) ? 1 : 0;
        const int u = p ^ q;
        int bin = (p << 2) | (u << 1) | (u ^ t);
        if (!valid) bin = 4;   // atan2(0,0)=0 -> bin 4

        const int hidx = (bin << 9) + tid;   // SLOTS=512
        float2 h = s_h[hidx];
        h.x += mag;
        h.y += 1.0f;
        s_h[hidx] = h;
    }

    // tree-reduce 512 -> 1 per bin (pad slots are zero)
    int sh = 8;
    for (int off = 256; off >= 1; off >>= 1, --sh) {
        __syncthreads();
        for (int w = tid; w < NBINS * off; w += NTH) {
            const int b = w >> sh;
            const int t = w & (off - 1);
            float2 lo = s_h[(b << 9) + t];
            float2 hi = s_h[(b << 9) + t + off];
            lo.x += hi.x; lo.y += hi.y;
            s_h[(b << 9) + t] = lo;
        }
    }
    __syncthreads();

    if (tid < NBINS) {
        const float2 h = s_h[tid << 9];
        if (CHUNKS == 1) {
            out[m * NBINS + tid] = (h.y != 0.0f) ? (h.x / fmaxf(h.y, 1.0f)) : 0.0f;
        } else {
            float* p = ws + bid * 16;
            p[tid]     = h.x;
            p[tid + 8] = h.y;
        }
    }
}

__global__ __launch_bounds__(FNTH) void finalize_kernel(
    const float* __restrict__ ws, float* __restrict__ out, int M, int chunks)
{
    const int i = blockIdx.x * FNTH + threadIdx.x;
    if (i >= M * NBINS) return;
    const int m = i >> 3;
    const int b = i & 7;
    float s = 0.0f, c = 0.0f;
    for (int ch = 0; ch < chunks; ++ch) {
        const float* p = ws + (size_t)(m * chunks + ch) * 16;
        s += p[b];
        c += p[b + 8];
    }
    out[i] = (c != 0.0f) ? (s / fmaxf(c, 1.0f)) : 0.0f;
}

extern "C" void kernel_launch(void* const* d_in, const int* in_sizes, int n_in,
                              void* d_out, int out_size, void* d_ws, size_t ws_size,
                              hipStream_t stream) {
    const float* flows = (const float*)d_in[0];
    const float* boxes = (const float*)d_in[1];
    float* out = (float*)d_out;
    const int M = in_sizes[1] / 5;               // 512

    const int CH = 4;
    const size_t part_need = (size_t)M * CH * 16 * sizeof(float);      // 128 KB
    if (ws_size >= part_need) {
        velhist_kernel<CH><<<dim3(M * CH), dim3(NTH), 0, stream>>>(
            flows, boxes, (float*)d_ws, nullptr);
        finalize_kernel<<<dim3((M * NBINS + FNTH - 1) / FNTH), dim3(FNTH), 0, stream>>>(
            (const float*)d_ws, out, M, CH);
    } else {
        velhist_kernel<1><<<dim3(M), dim3(NTH), 0, stream>>>(
            flows, boxes, nullptr, out);
    }
}